// Round 1
// 95.542 us; speedup vs baseline: 1.0393x; 1.0393x over previous
//
#include <hip/hip_runtime.h>
#include <stdint.h>

#define CI 256
#define CO 256
#define HW 4096          // 64*64 pixels per image
#define PT 64            // pixel tile per block
#define QP 264           // Qlds row stride in shorts: 528 B (16B-aligned, 132 words -> 4-bank row skew)

typedef __attribute__((ext_vector_type(8))) short short8;   // 8 bf16 = 4 VGPRs
typedef __attribute__((ext_vector_type(4))) float float4v;  // MFMA C/D frag

__device__ __forceinline__ float fcomp(const float4& v, int c) {
    return c == 0 ? v.x : c == 1 ? v.y : c == 2 ? v.z : v.w;
}

// ---------- weight prep: fp32 -> bf16 (RNE) + per-row sums ----------
__global__ void prep_kernel(const float* __restrict__ w,
                            ushort* __restrict__ w16,
                            float* __restrict__ wsum) {
    const int o = blockIdx.x;        // one output row per 64-thread block
    const int lane = threadIdx.x;    // 0..63
    float4 v = ((const float4*)(w + o * CI))[lane];
    auto cvt = [](float f) -> ushort {
        uint32_t u = __float_as_uint(f);
        return (ushort)((u + 0x7FFFu + ((u >> 16) & 1u)) >> 16);   // RNE
    };
    ushort4 q;
    q.x = cvt(v.x); q.y = cvt(v.y); q.z = cvt(v.z); q.w = cvt(v.w);
    ((ushort4*)(w16 + o * CI))[lane] = q;
    float s = v.x + v.y + v.z + v.w;
    for (int off = 32; off >= 1; off >>= 1) s += __shfl_down(s, off);
    if (lane == 0) wsum[o] = s;
}

// ---------- fused quantize + 1x1-conv GEMM (single pass over x) ----------
// 512 threads = 8 waves. Each thread owns 8 channels x 4 pixels of x in
// registers (x read from HBM exactly once). 3 barriers per block total;
// the whole K=256 MFMA sweep runs with no barriers.
__global__ __launch_bounds__(512, 4)
void noise_conv_kernel(const float* __restrict__ x,
                       const ushort* __restrict__ w16,
                       const float* __restrict__ wsum,
                       const float* __restrict__ bias,
                       float* __restrict__ out) {
    __shared__ ushort Qlds[PT][QP];            // quantized bf16 tile [p][c], 33 KB
    __shared__ float4 wmin[8][16];             // per-wave partial min [wave][pg]
    __shared__ float4 wmax[8][16];
    __shared__ float cmin_s[PT], s_s[PT], inv_s[PT];

    const int t = threadIdx.x;
    const int blk = blockIdx.x;                // 512 = 8 imgs * 64 tiles
    const int img = blk >> 6;
    const int p0 = (blk & 63) * PT;
    const float* xb = x + (size_t)img * CI * HW + p0;
    float* outb = out + (size_t)img * CO * HW + p0;

    const int pg = t & 15;        // 4-pixel group (float4)
    const int slice = t >> 4;     // 0..31 : 8-channel slice

    // ---- phase 1: load x once (8 ch x 4 px per thread), per-pixel min/max ----
    float4 xv[8];
    #pragma unroll
    for (int i = 0; i < 8; ++i)
        xv[i] = ((const float4*)(xb + (size_t)(slice * 8 + i) * HW))[pg];

    float4 vmin = xv[0], vmax = xv[0];
    #pragma unroll
    for (int i = 1; i < 8; ++i) {
        vmin.x = fminf(vmin.x, xv[i].x); vmax.x = fmaxf(vmax.x, xv[i].x);
        vmin.y = fminf(vmin.y, xv[i].y); vmax.y = fmaxf(vmax.y, xv[i].y);
        vmin.z = fminf(vmin.z, xv[i].z); vmax.z = fmaxf(vmax.z, xv[i].z);
        vmin.w = fminf(vmin.w, xv[i].w); vmax.w = fmaxf(vmax.w, xv[i].w);
    }
    // in-wave reduce across the 4 slices resident in this wave (lanes ^16, ^32)
    #pragma unroll
    for (int off = 16; off <= 32; off <<= 1) {
        vmin.x = fminf(vmin.x, __shfl_xor(vmin.x, off));
        vmin.y = fminf(vmin.y, __shfl_xor(vmin.y, off));
        vmin.z = fminf(vmin.z, __shfl_xor(vmin.z, off));
        vmin.w = fminf(vmin.w, __shfl_xor(vmin.w, off));
        vmax.x = fmaxf(vmax.x, __shfl_xor(vmax.x, off));
        vmax.y = fmaxf(vmax.y, __shfl_xor(vmax.y, off));
        vmax.z = fmaxf(vmax.z, __shfl_xor(vmax.z, off));
        vmax.w = fmaxf(vmax.w, __shfl_xor(vmax.w, off));
    }
    const int wv = t >> 6;        // wave id 0..7
    if ((t & 63) < 16) { wmin[wv][pg] = vmin; wmax[wv][pg] = vmax; }
    __syncthreads();

    // 64 threads finalize: one pixel each, reduce 8 wave-partials
    if (t < 64) {
        const int g = t >> 2, c = t & 3;
        float mn = fcomp(wmin[0][g], c), mx = fcomp(wmax[0][g], c);
        #pragma unroll
        for (int w = 1; w < 8; ++w) {
            mn = fminf(mn, fcomp(wmin[w][g], c));
            mx = fmaxf(mx, fcomp(wmax[w][g], c));
        }
        const float sc = (mx - mn) / 63.0f;    // match ref: /63
        cmin_s[t] = mn;
        s_s[t] = sc;
        inv_s[t] = 1.0f / sc;
    }
    __syncthreads();

    // ---- phase 2: quantize from registers -> full-K LDS tile ----
    {
        float cm[4], iv[4];
        #pragma unroll
        for (int c2 = 0; c2 < 4; ++c2) {
            cm[c2] = cmin_s[pg * 4 + c2];
            iv[c2] = inv_s[pg * 4 + c2];
        }
        #pragma unroll
        for (int c2 = 0; c2 < 4; ++c2) {
            uint32_t wds[4];
            #pragma unroll
            for (int j = 0; j < 4; ++j) {
                const float q0 = rintf((fcomp(xv[2 * j],     c2) - cm[c2]) * iv[c2]);
                const float q1 = rintf((fcomp(xv[2 * j + 1], c2) - cm[c2]) * iv[c2]);
                // q is an exact small integer -> low 16 bits of the f32 are 0
                wds[j] = (__float_as_uint(q0) >> 16) | (__float_as_uint(q1) & 0xFFFF0000u);
            }
            *((uint4*)&Qlds[pg * 4 + c2][slice * 8]) =
                make_uint4(wds[0], wds[1], wds[2], wds[3]);
        }
    }
    __syncthreads();

    // ---- phase 3: barrier-free MFMA sweep over K=256 ----
    const int lane = t & 63;
    const int row16 = lane & 15;
    const int quad = lane >> 4;

    float4v acc[2][4];
    #pragma unroll
    for (int m = 0; m < 2; ++m)
        #pragma unroll
        for (int n = 0; n < 4; ++n) {
            float4v z = {0.0f, 0.0f, 0.0f, 0.0f};
            acc[m][n] = z;
        }

    const ushort* wrow = w16 + (size_t)(wv * 32 + row16) * CI;
    #pragma unroll
    for (int ks = 0; ks < 8; ++ks) {
        const int kk = ks * 32 + quad * 8;
        short8 afr[2], bfr[4];
        afr[0] = *((const short8*)(wrow + kk));
        afr[1] = *((const short8*)(wrow + 16 * CI + kk));
        #pragma unroll
        for (int n = 0; n < 4; ++n)
            bfr[n] = *((const short8*)&Qlds[n * 16 + row16][kk]);
        #pragma unroll
        for (int m = 0; m < 2; ++m)
            #pragma unroll
            for (int n = 0; n < 4; ++n)
                acc[m][n] = __builtin_amdgcn_mfma_f32_16x16x32_bf16(
                    afr[m], bfr[n], acc[m][n], 0, 0, 0);
    }

    // ---- epilogue: rescale + cmin*wsum + bias, store ----
    #pragma unroll
    for (int m = 0; m < 2; ++m) {
        const int ob = wv * 32 + m * 16 + quad * 4;
        const float4 w4 = *((const float4*)(wsum + ob));
        const float4 b4 = *((const float4*)(bias + ob));
        const float wr[4] = {w4.x, w4.y, w4.z, w4.w};
        const float br[4] = {b4.x, b4.y, b4.z, b4.w};
        #pragma unroll
        for (int n = 0; n < 4; ++n) {
            const int pl = n * 16 + row16;
            const float sc = s_s[pl];
            const float cm2 = cmin_s[pl];
            float* op = outb + pl;
            #pragma unroll
            for (int r = 0; r < 4; ++r) {
                op[(size_t)(ob + r) * HW] =
                    acc[m][n][r] * sc + cm2 * wr[r] + br[r];
            }
        }
    }
}

extern "C" void kernel_launch(void* const* d_in, const int* in_sizes, int n_in,
                              void* d_out, int out_size, void* d_ws, size_t ws_size,
                              hipStream_t stream) {
    const float* x    = (const float*)d_in[0];
    const float* w    = (const float*)d_in[1];
    const float* bias = (const float*)d_in[2];
    float* out = (float*)d_out;

    ushort* w16 = (ushort*)d_ws;                                   // 128 KiB
    float* wsum = (float*)((char*)d_ws + (size_t)CO * CI * sizeof(ushort));

    prep_kernel<<<CO, 64, 0, stream>>>(w, w16, wsum);
    noise_conv_kernel<<<512, 512, 0, stream>>>(x, w16, wsum, bias, out);
}